// Round 2
// baseline (1005.056 us; speedup 1.0000x reference)
//
#include <hip/hip_runtime.h>
#include <hip/hip_bf16.h>
#include <math.h>

#define B   2
#define TQ  1024
#define TKV 1024
#define D   1024
#define H   16
#define HD  64
#define P   64     // 2*SPAN
#define SPAN 32

#define NEG_INF (-3.0e38f)

// ---------------- workspace layout (in floats) ----------------
static constexpr size_t Q_OFF    = 0;
static constexpr size_t K_OFF    = Q_OFF + (size_t)2048 * 1024;
static constexpr size_t V_OFF    = K_OFF + (size_t)2048 * 1024;
static constexpr size_t CTX_OFF  = V_OFF + (size_t)2048 * 1024;
static constexpr size_t RE_OFF   = CTX_OFF + (size_t)2048 * 1024;   // 64*1024
static constexpr size_t POSK_OFF = RE_OFF + (size_t)64 * 1024;
static constexpr size_t POSQ_OFF = POSK_OFF + (size_t)64 * 1024;
static constexpr size_t C2P_OFF  = POSQ_OFF + (size_t)64 * 1024;    // B*H*TQ*P = 2M floats
static constexpr size_t P2C_OFF  = C2P_OFF + (size_t)B * H * TQ * P;
static constexpr size_t WS_FLOATS = P2C_OFF + (size_t)B * H * TKV * P;
static constexpr size_t TAB_OFF_BYTES = WS_FLOATS * sizeof(float);  // 2047 uchar

// ---------------- LayerNorm over rel_emb rows ----------------
__global__ __launch_bounds__(256) void ln_kernel(const float* __restrict__ x,
    const float* __restrict__ g, const float* __restrict__ bta, float* __restrict__ out) {
  const int row = blockIdx.x;
  const float* xr = x + (size_t)row * D;
  const int tid = threadIdx.x;
  __shared__ float red[4];
  float s = 0.f;
  for (int i = tid; i < D; i += 256) s += xr[i];
  #pragma unroll
  for (int off = 32; off; off >>= 1) s += __shfl_down(s, off);
  if ((tid & 63) == 0) red[tid >> 6] = s;
  __syncthreads();
  float mu = (red[0] + red[1] + red[2] + red[3]) * (1.0f / D);
  __syncthreads();
  float vs = 0.f;
  for (int i = tid; i < D; i += 256) { float dd = xr[i] - mu; vs += dd * dd; }
  #pragma unroll
  for (int off = 32; off; off >>= 1) vs += __shfl_down(vs, off);
  if ((tid & 63) == 0) red[tid >> 6] = vs;
  __syncthreads();
  float var = (red[0] + red[1] + red[2] + red[3]) * (1.0f / D);
  float rs = rsqrtf(var + 1e-5f);
  for (int i = tid; i < D; i += 256)
    out[(size_t)row * D + i] = (xr[i] - mu) * rs * g[i] + bta[i];
}

// ---------------- log-bucket position table ----------------
// tab[d+1023] = clip(bucket(d)+32, 0, 63), d = q - k
// Double precision + boundary snap: ad=127 sits EXACTLY on a ceil boundary
// (log(127/16)/log(127/16)*15 == 15); 1-ulp mismatch between runtime log and
// compile-time-folded log flips ceil -> wrong bucket. Snap |x-round(x)|<1e-9
// to the integer (real-math semantics). All other boundaries are >=2e-3 away.
__global__ void tab_kernel(unsigned char* __restrict__ tab) {
  int i = blockIdx.x * 256 + threadIdx.x;
  if (i >= 2047) return;
  int d = i - 1023;
  int ad = d < 0 ? -d : d;
  int bucket;
  if (ad <= 16) {
    bucket = d;
  } else {
    double x = log((double)ad / 16.0) / log(127.0 / 16.0) * 15.0;
    double xr = floor(x + 0.5);
    double xc = (fabs(x - xr) < 1e-9) ? xr : ceil(x);
    int li = (int)xc + 16;
    bucket = (d > 0) ? li : -li;
  }
  int t = bucket + SPAN;
  t = t < 0 ? 0 : (t > 63 ? 63 : t);
  tab[i] = (unsigned char)t;
}

// ---------------- generic fp32 GEMM: C[M,N] = A[M,K] @ W[N,K]^T + bias ----------------
// BM=BN=64, BK=16, 256 threads, 4x4 micro-tile. M,N multiples of 64; K multiple of 16.
__global__ __launch_bounds__(256) void gemm_bias(const float* __restrict__ A,
    const float* __restrict__ W, const float* __restrict__ bias,
    float* __restrict__ C, int M, int N, int K) {
  __shared__ __align__(16) float As[16][64];  // [k][m]
  __shared__ __align__(16) float Ws[16][64];  // [k][n]
  const int tid = threadIdx.x;
  const int bm = blockIdx.y * 64, bn = blockIdx.x * 64;
  const int tx = tid & 15, ty = tid >> 4;
  const int lm = tid >> 4, lk = tid & 15;
  float acc[4][4] = {};
  for (int k0 = 0; k0 < K; k0 += 16) {
    __syncthreads();
    #pragma unroll
    for (int r = 0; r < 4; r++) {
      As[lk][lm + 16 * r] = A[(size_t)(bm + lm + 16 * r) * K + k0 + lk];
      Ws[lk][lm + 16 * r] = W[(size_t)(bn + lm + 16 * r) * K + k0 + lk];
    }
    __syncthreads();
    #pragma unroll
    for (int kk = 0; kk < 16; kk++) {
      float4 a4 = *(const float4*)&As[kk][ty * 4];
      float4 b4 = *(const float4*)&Ws[kk][tx * 4];
      float av[4] = {a4.x, a4.y, a4.z, a4.w};
      float bv[4] = {b4.x, b4.y, b4.z, b4.w};
      #pragma unroll
      for (int i = 0; i < 4; i++)
        #pragma unroll
        for (int j = 0; j < 4; j++)
          acc[i][j] += av[i] * bv[j];
    }
  }
  #pragma unroll
  for (int i = 0; i < 4; i++) {
    int m = bm + ty * 4 + i;
    #pragma unroll
    for (int j = 0; j < 4; j++) {
      int n = bn + tx * 4 + j;
      float bb = bias ? bias[n] : 0.0f;
      C[(size_t)m * N + n] = acc[i][j] + bb;
    }
  }
}

// ---------------- rel projection: out[(bh*T + t)*64 + p] = sum_d X[(b*T+t)*D + h*64+d] * POS[p*D + h*64+d]
__global__ __launch_bounds__(256) void relproj_kernel(const float* __restrict__ X,
    const float* __restrict__ POS, float* __restrict__ out) {
  const int bh = blockIdx.y, b = bh >> 4, h = bh & 15;
  const int t0 = blockIdx.x * 64;
  __shared__ __align__(16) float sx[64][68];  // [d][t]
  __shared__ __align__(16) float sp[64][68];  // [d][p]
  const int tid = threadIdx.x;
  for (int i = tid; i < 4096; i += 256) {
    int r = i >> 6, d = i & 63;
    sx[d][r] = X[((size_t)b * TQ + t0 + r) * D + h * HD + d];
    sp[d][r] = POS[(size_t)r * D + h * HD + d];
  }
  __syncthreads();
  const int tx = tid & 15, ty = tid >> 4;
  float acc[4][4] = {};
  for (int d = 0; d < 64; d++) {
    float4 a4 = *(const float4*)&sx[d][ty * 4];
    float4 b4 = *(const float4*)&sp[d][tx * 4];
    float av[4] = {a4.x, a4.y, a4.z, a4.w};
    float bv[4] = {b4.x, b4.y, b4.z, b4.w};
    #pragma unroll
    for (int i = 0; i < 4; i++)
      #pragma unroll
      for (int j = 0; j < 4; j++)
        acc[i][j] += av[i] * bv[j];
  }
  #pragma unroll
  for (int i = 0; i < 4; i++)
    #pragma unroll
    for (int j = 0; j < 4; j++)
      out[((size_t)bh * TQ + t0 + ty * 4 + i) * P + tx * 4 + j] = acc[i][j];
}

// ---------------- flash-style attention with disentangled bias ----------------
// grid (TQ/16, B*H), 256 threads. QB=16, KB=64.
__global__ __launch_bounds__(256) void attn_kernel(
    const float* __restrict__ qb, const float* __restrict__ kb, const float* __restrict__ vb,
    const float* __restrict__ c2p, const float* __restrict__ p2c,
    const unsigned char* __restrict__ mask, const unsigned char* __restrict__ tab,
    float* __restrict__ ctx) {
  const int bh = blockIdx.y, b = bh >> 4, h = bh & 15;
  const int q0 = blockIdx.x * 16;
  const int tid = threadIdx.x;

  __shared__ __align__(16) float sq[16][65];
  __shared__ __align__(16) float sc2p[16][68];
  __shared__ __align__(16) float skT[64][68];   // [d][kj]
  __shared__ __align__(16) float sv[64][68];    // [kj][d]
  __shared__ __align__(16) float sp2c[64][68];  // [kj][p]
  __shared__ __align__(16) float ss[16][68];    // probs
  __shared__ __align__(16) float sacc[16][68];
  __shared__ float sm[16], sl[16], sfac[16];
  __shared__ unsigned char stab[2048];
  __shared__ unsigned char smask[64];

  for (int i = tid; i < 1024; i += 256) {
    int qi = i >> 6, d = i & 63;
    sq[qi][d]   = qb[((size_t)b * TQ + q0 + qi) * D + h * HD + d];
    sc2p[qi][d] = c2p[((size_t)bh * TQ + q0 + qi) * P + d];
    sacc[qi][d] = 0.f;
  }
  for (int i = tid; i < 2047; i += 256) stab[i] = tab[i];
  if (tid < 16) { sm[tid] = NEG_INF; sl[tid] = 0.f; }

  const float inv_s  = 0.07216878364870323f;  // 1/sqrt(192)
  const float inv_ps = 0.08838834764831845f;  // 1/sqrt(128)
  const int qi = tid >> 4, tx = tid & 15;

  for (int kt = 0; kt < TKV / 64; kt++) {
    const int k0 = kt * 64;
    __syncthreads();  // protect LDS buffers from previous iteration readers
    for (int i = tid; i < 4096; i += 256) {
      int kj = i >> 6, d = i & 63;
      size_t g = ((size_t)b * TKV + k0 + kj) * D + h * HD + d;
      skT[d][kj]  = kb[g];
      sv[kj][d]   = vb[g];
      sp2c[kj][d] = p2c[((size_t)bh * TKV + k0 + kj) * P + d];
    }
    if (tid < 64) smask[tid] = mask[(size_t)b * TKV + k0 + tid];
    __syncthreads();

    // ---- scores: each thread owns (qi, kj0..kj0+3)
    const int kj0 = tx * 4;
    float s0 = 0, s1 = 0, s2 = 0, s3 = 0;
    #pragma unroll
    for (int d = 0; d < 64; d++) {
      float a = sq[qi][d];
      float4 bk = *(const float4*)&skT[d][kj0];
      s0 += a * bk.x; s1 += a * bk.y; s2 += a * bk.z; s3 += a * bk.w;
    }
    float val[4] = {s0, s1, s2, s3};
    float lmax = NEG_INF;
    #pragma unroll
    for (int j = 0; j < 4; j++) {
      int kj = kj0 + j;
      int delta = (q0 + qi) - (k0 + kj) + 1023;
      int tbi = stab[delta];
      float vv = val[j] * inv_s + (sc2p[qi][tbi] + sp2c[kj][tbi]) * inv_ps;
      if (smask[kj]) vv = NEG_INF;
      val[j] = vv;
      lmax = fmaxf(lmax, vv);
    }
    #pragma unroll
    for (int off = 1; off < 16; off <<= 1) lmax = fmaxf(lmax, __shfl_xor(lmax, off));
    float mold = sm[qi];
    float mnew = fmaxf(mold, lmax);
    float p[4], psum = 0.f;
    #pragma unroll
    for (int j = 0; j < 4; j++) { p[j] = __expf(val[j] - mnew); psum += p[j]; }
    #pragma unroll
    for (int off = 1; off < 16; off <<= 1) psum += __shfl_xor(psum, off);
    float fac = __expf(mold - mnew);
    if (tx == 0) { sm[qi] = mnew; sl[qi] = sl[qi] * fac + psum; sfac[qi] = fac; }
    *(float4*)&ss[qi][kj0] = make_float4(p[0], p[1], p[2], p[3]);
    __syncthreads();

    // ---- accumulate: each thread owns (qi, d0..d0+3)
    const int d0 = tx * 4;
    float fac2 = sfac[qi];
    float4 a4 = *(float4*)&sacc[qi][d0];
    a4.x *= fac2; a4.y *= fac2; a4.z *= fac2; a4.w *= fac2;
    #pragma unroll
    for (int j = 0; j < 64; j++) {
      float pj = ss[qi][j];
      float4 vv = *(const float4*)&sv[j][d0];
      a4.x += pj * vv.x; a4.y += pj * vv.y; a4.z += pj * vv.z; a4.w += pj * vv.w;
    }
    *(float4*)&sacc[qi][d0] = a4;
  }
  __syncthreads();
  const int d0 = tx * 4;
  float invl = 1.0f / sl[qi];
  float4 a4 = *(float4*)&sacc[qi][d0];
  float4 o = make_float4(a4.x * invl, a4.y * invl, a4.z * invl, a4.w * invl);
  *(float4*)&ctx[((size_t)b * TQ + q0 + qi) * D + h * HD + d0] = o;
}

extern "C" void kernel_launch(void* const* d_in, const int* in_sizes, int n_in,
                              void* d_out, int out_size, void* d_ws, size_t ws_size,
                              hipStream_t stream) {
  const float* query = (const float*)d_in[0];
  const float* kv    = (const float*)d_in[1];
  const float* Wq  = (const float*)d_in[2];   const float* bq  = (const float*)d_in[3];
  const float* Wk  = (const float*)d_in[4];   const float* bk  = (const float*)d_in[5];
  const float* Wv  = (const float*)d_in[6];   const float* bv  = (const float*)d_in[7];
  const float* Wo  = (const float*)d_in[8];   const float* bo  = (const float*)d_in[9];
  const float* Wpk = (const float*)d_in[10];  const float* bpk = (const float*)d_in[11];
  const float* Wpq = (const float*)d_in[12];  const float* bpq = (const float*)d_in[13];
  const float* rel_emb = (const float*)d_in[14];
  const float* ln_g = (const float*)d_in[15];
  const float* ln_b = (const float*)d_in[16];
  const unsigned char* amask = (const unsigned char*)d_in[17];

  float* ws = (float*)d_ws;
  float* qbuf   = ws + Q_OFF;
  float* kbuf   = ws + K_OFF;
  float* vbuf   = ws + V_OFF;
  float* ctxbuf = ws + CTX_OFF;
  float* rebuf  = ws + RE_OFF;
  float* poskbuf = ws + POSK_OFF;
  float* posqbuf = ws + POSQ_OFF;
  float* c2pbuf = ws + C2P_OFF;
  float* p2cbuf = ws + P2C_OFF;
  unsigned char* tab = (unsigned char*)d_ws + TAB_OFF_BYTES;

  // 1. LayerNorm of rel_emb
  ln_kernel<<<64, 256, 0, stream>>>(rel_emb, ln_g, ln_b, rebuf);
  // 2. bucket table
  tab_kernel<<<8, 256, 0, stream>>>(tab);
  // 3. positional projections (64 x 1024 @ 1024 x 1024^T)
  gemm_bias<<<dim3(16, 1), 256, 0, stream>>>(rebuf, Wpk, bpk, poskbuf, 64, 1024, 1024);
  gemm_bias<<<dim3(16, 1), 256, 0, stream>>>(rebuf, Wpq, bpq, posqbuf, 64, 1024, 1024);
  // 4. Q/K/V projections (2048 x 1024 @ 1024 x 1024^T)
  gemm_bias<<<dim3(16, 32), 256, 0, stream>>>(query, Wq, bq, qbuf, 2048, 1024, 1024);
  gemm_bias<<<dim3(16, 32), 256, 0, stream>>>(kv,    Wk, bk, kbuf, 2048, 1024, 1024);
  gemm_bias<<<dim3(16, 32), 256, 0, stream>>>(kv,    Wv, bv, vbuf, 2048, 1024, 1024);
  // 5. c2p = q . pos_k, p2c = k . pos_q (per b,h)
  relproj_kernel<<<dim3(16, 32), 256, 0, stream>>>(qbuf, poskbuf, c2pbuf);
  relproj_kernel<<<dim3(16, 32), 256, 0, stream>>>(kbuf, posqbuf, p2cbuf);
  // 6. attention
  attn_kernel<<<dim3(64, 32), 256, 0, stream>>>(qbuf, kbuf, vbuf, c2pbuf, p2cbuf,
                                                amask, tab, ctxbuf);
  // 7. output projection -> d_out
  gemm_bias<<<dim3(16, 32), 256, 0, stream>>>(ctxbuf, Wo, bo, (float*)d_out, 2048, 1024, 1024);
}

// Round 3
// 644.830 us; speedup vs baseline: 1.5586x; 1.5586x over previous
//
#include <hip/hip_runtime.h>
#include <hip/hip_bf16.h>
#include <math.h>

#define B   2
#define TQ  1024
#define TKV 1024
#define D   1024
#define H   16
#define HD  64
#define P   64     // 2*SPAN
#define SPAN 32

#define NEG_INF (-3.0e38f)

typedef __attribute__((ext_vector_type(8))) short bf16x8;
typedef __attribute__((ext_vector_type(4))) float f32x4;

// ---------------- workspace layout (in floats) ----------------
static constexpr size_t Q_OFF    = 0;
static constexpr size_t K_OFF    = Q_OFF + (size_t)2048 * 1024;
static constexpr size_t V_OFF    = K_OFF + (size_t)2048 * 1024;
static constexpr size_t CTX_OFF  = V_OFF + (size_t)2048 * 1024;
static constexpr size_t RE_OFF   = CTX_OFF + (size_t)2048 * 1024;   // 64*1024
static constexpr size_t POSK_OFF = RE_OFF + (size_t)64 * 1024;
static constexpr size_t POSQ_OFF = POSK_OFF + (size_t)64 * 1024;
static constexpr size_t C2P_OFF  = POSQ_OFF + (size_t)64 * 1024;    // B*H*TQ*P = 2M floats
static constexpr size_t P2C_OFF  = C2P_OFF + (size_t)B * H * TQ * P;
static constexpr size_t WS_FLOATS = P2C_OFF + (size_t)B * H * TKV * P;
static constexpr size_t TAB_OFF_BYTES = WS_FLOATS * sizeof(float);  // 2047 uchar

// split x into hi (bit-truncated bf16) + lo (RN bf16 of exact residual)
__device__ __forceinline__ void split2(float x, unsigned short& h, unsigned short& l) {
  unsigned int u = __float_as_uint(x);
  h = (unsigned short)(u >> 16);
  float r = x - __uint_as_float(u & 0xffff0000u);   // exact
  unsigned int v = __float_as_uint(r);
  v += 0x7fffu + ((v >> 16) & 1u);                  // RN-even
  l = (unsigned short)(v >> 16);
}

// ---------------- LayerNorm over rel_emb rows ----------------
__global__ __launch_bounds__(256) void ln_kernel(const float* __restrict__ x,
    const float* __restrict__ g, const float* __restrict__ bta, float* __restrict__ out) {
  const int row = blockIdx.x;
  const float* xr = x + (size_t)row * D;
  const int tid = threadIdx.x;
  __shared__ float red[4];
  float s = 0.f;
  for (int i = tid; i < D; i += 256) s += xr[i];
  #pragma unroll
  for (int off = 32; off; off >>= 1) s += __shfl_down(s, off);
  if ((tid & 63) == 0) red[tid >> 6] = s;
  __syncthreads();
  float mu = (red[0] + red[1] + red[2] + red[3]) * (1.0f / D);
  __syncthreads();
  float vs = 0.f;
  for (int i = tid; i < D; i += 256) { float dd = xr[i] - mu; vs += dd * dd; }
  #pragma unroll
  for (int off = 32; off; off >>= 1) vs += __shfl_down(vs, off);
  if ((tid & 63) == 0) red[tid >> 6] = vs;
  __syncthreads();
  float var = (red[0] + red[1] + red[2] + red[3]) * (1.0f / D);
  float rs = rsqrtf(var + 1e-5f);
  for (int i = tid; i < D; i += 256)
    out[(size_t)row * D + i] = (xr[i] - mu) * rs * g[i] + bta[i];
}

// ---------------- log-bucket position table ----------------
__global__ void tab_kernel(unsigned char* __restrict__ tab) {
  int i = blockIdx.x * 256 + threadIdx.x;
  if (i >= 2047) return;
  int d = i - 1023;
  int ad = d < 0 ? -d : d;
  int bucket;
  if (ad <= 16) {
    bucket = d;
  } else {
    double x = log((double)ad / 16.0) / log(127.0 / 16.0) * 15.0;
    double xr = floor(x + 0.5);
    double xc = (fabs(x - xr) < 1e-9) ? xr : ceil(x);
    int li = (int)xc + 16;
    bucket = (d > 0) ? li : -li;
  }
  int t = bucket + SPAN;
  t = t < 0 ? 0 : (t > 63 ? 63 : t);
  tab[i] = (unsigned char)t;
}

// ---------------- fp32 GEMM (small pos projections only) ----------------
__global__ __launch_bounds__(256) void gemm_bias(const float* __restrict__ A,
    const float* __restrict__ W, const float* __restrict__ bias,
    float* __restrict__ C, int M, int N, int K) {
  __shared__ __align__(16) float As[16][64];
  __shared__ __align__(16) float Ws[16][64];
  const int tid = threadIdx.x;
  const int bm = blockIdx.y * 64, bn = blockIdx.x * 64;
  const int tx = tid & 15, ty = tid >> 4;
  const int lm = tid >> 4, lk = tid & 15;
  float acc[4][4] = {};
  for (int k0 = 0; k0 < K; k0 += 16) {
    __syncthreads();
    #pragma unroll
    for (int r = 0; r < 4; r++) {
      As[lk][lm + 16 * r] = A[(size_t)(bm + lm + 16 * r) * K + k0 + lk];
      Ws[lk][lm + 16 * r] = W[(size_t)(bn + lm + 16 * r) * K + k0 + lk];
    }
    __syncthreads();
    #pragma unroll
    for (int kk = 0; kk < 16; kk++) {
      float4 a4 = *(const float4*)&As[kk][ty * 4];
      float4 b4 = *(const float4*)&Ws[kk][tx * 4];
      float av[4] = {a4.x, a4.y, a4.z, a4.w};
      float bv[4] = {b4.x, b4.y, b4.z, b4.w};
      #pragma unroll
      for (int i = 0; i < 4; i++)
        #pragma unroll
        for (int j = 0; j < 4; j++)
          acc[i][j] += av[i] * bv[j];
    }
  }
  #pragma unroll
  for (int i = 0; i < 4; i++) {
    int m = bm + ty * 4 + i;
    #pragma unroll
    for (int j = 0; j < 4; j++) {
      int n = bn + tx * 4 + j;
      float bb = bias ? bias[n] : 0.0f;
      C[(size_t)m * N + n] = acc[i][j] + bb;
    }
  }
}

// ---------------- split-bf16 MFMA GEMM: C[M,N] = A @ W^T + bias ----------------
// BM=128, BN=64, BK=32, 256 threads = 4 waves (2x2), wave tile 64x32.
// C = Ah*Bh + Ah*Bl + Al*Bh (split compensation, ~fp32 accuracy).
// blockIdx.z selects one of up to 3 (A,W,bias,C) problem instances.
__global__ __launch_bounds__(256) void gemm_split(
    const float* __restrict__ A0, const float* __restrict__ A1, const float* __restrict__ A2,
    const float* __restrict__ W0, const float* __restrict__ W1, const float* __restrict__ W2,
    const float* __restrict__ b0, const float* __restrict__ b1, const float* __restrict__ b2,
    float* __restrict__ C0, float* __restrict__ C1, float* __restrict__ C2,
    int M, int N, int K) {
  const int z = blockIdx.z;
  const float* A = (z == 0) ? A0 : (z == 1) ? A1 : A2;
  const float* W = (z == 0) ? W0 : (z == 1) ? W1 : W2;
  const float* bias = (z == 0) ? b0 : (z == 1) ? b1 : b2;
  float* C = (z == 0) ? C0 : (z == 1) ? C1 : C2;

  __shared__ short sAhi[128 * 32];
  __shared__ short sAlo[128 * 32];
  __shared__ short sBhi[64 * 32];
  __shared__ short sBlo[64 * 32];

  const int t = threadIdx.x;
  const int bm = blockIdx.y * 128, bn = blockIdx.x * 64;
  const int wid = t >> 6, lane = t & 63;
  const int wr = wid >> 1, wc = wid & 1;
  const int fr = lane & 15, fo = (lane >> 4) * 8;

  f32x4 acc[4][2];
  #pragma unroll
  for (int i = 0; i < 4; i++)
    #pragma unroll
    for (int j = 0; j < 2; j++)
      acc[i][j] = (f32x4){0.f, 0.f, 0.f, 0.f};

  const int srow = t >> 3;          // 0..31
  const int scol = (t & 7) * 4;     // 0,4,..,28

  for (int k0 = 0; k0 < K; k0 += 32) {
    // ---- stage A (128x32) and B (64x32): f32 -> hi/lo bf16 in LDS
    #pragma unroll
    for (int i = 0; i < 4; i++) {
      int row = srow + 32 * i;
      float4 a = *(const float4*)&A[(size_t)(bm + row) * K + k0 + scol];
      unsigned short h0, h1, h2, h3, l0, l1, l2, l3;
      split2(a.x, h0, l0); split2(a.y, h1, l1); split2(a.z, h2, l2); split2(a.w, h3, l3);
      *(short4*)&sAhi[row * 32 + scol] = make_short4((short)h0, (short)h1, (short)h2, (short)h3);
      *(short4*)&sAlo[row * 32 + scol] = make_short4((short)l0, (short)l1, (short)l2, (short)l3);
    }
    #pragma unroll
    for (int i = 0; i < 2; i++) {
      int row = srow + 32 * i;
      float4 a = *(const float4*)&W[(size_t)(bn + row) * K + k0 + scol];
      unsigned short h0, h1, h2, h3, l0, l1, l2, l3;
      split2(a.x, h0, l0); split2(a.y, h1, l1); split2(a.z, h2, l2); split2(a.w, h3, l3);
      *(short4*)&sBhi[row * 32 + scol] = make_short4((short)h0, (short)h1, (short)h2, (short)h3);
      *(short4*)&sBlo[row * 32 + scol] = make_short4((short)l0, (short)l1, (short)l2, (short)l3);
    }
    __syncthreads();

    // ---- fragments + MFMA
    bf16x8 ah[4], al[4], bh[2], bl[2];
    #pragma unroll
    for (int mf = 0; mf < 4; mf++) {
      int r = (wr * 64 + mf * 16 + fr) * 32 + fo;
      ah[mf] = *(const bf16x8*)&sAhi[r];
      al[mf] = *(const bf16x8*)&sAlo[r];
    }
    #pragma unroll
    for (int nf = 0; nf < 2; nf++) {
      int r = (wc * 32 + nf * 16 + fr) * 32 + fo;
      bh[nf] = *(const bf16x8*)&sBhi[r];
      bl[nf] = *(const bf16x8*)&sBlo[r];
    }
    #pragma unroll
    for (int mf = 0; mf < 4; mf++)
      #pragma unroll
      for (int nf = 0; nf < 2; nf++) {
        acc[mf][nf] = __builtin_amdgcn_mfma_f32_16x16x32_bf16(ah[mf], bh[nf], acc[mf][nf], 0, 0, 0);
        acc[mf][nf] = __builtin_amdgcn_mfma_f32_16x16x32_bf16(ah[mf], bl[nf], acc[mf][nf], 0, 0, 0);
        acc[mf][nf] = __builtin_amdgcn_mfma_f32_16x16x32_bf16(al[mf], bh[nf], acc[mf][nf], 0, 0, 0);
      }
    __syncthreads();
  }

  // ---- epilogue: C/D layout col=lane&15, row=(lane>>4)*4+reg
  #pragma unroll
  for (int mf = 0; mf < 4; mf++) {
    int rbase = bm + wr * 64 + mf * 16 + (lane >> 4) * 4;
    #pragma unroll
    for (int nf = 0; nf < 2; nf++) {
      int col = bn + wc * 32 + nf * 16 + fr;
      float bb = bias[col];
      #pragma unroll
      for (int r = 0; r < 4; r++)
        C[(size_t)(rbase + r) * N + col] = acc[mf][nf][r] + bb;
    }
  }
}

// ---------------- rel projection ----------------
__global__ __launch_bounds__(256) void relproj_kernel(const float* __restrict__ X,
    const float* __restrict__ POS, float* __restrict__ out) {
  const int bh = blockIdx.y, b = bh >> 4, h = bh & 15;
  const int t0 = blockIdx.x * 64;
  __shared__ __align__(16) float sx[64][68];
  __shared__ __align__(16) float sp[64][68];
  const int tid = threadIdx.x;
  for (int i = tid; i < 4096; i += 256) {
    int r = i >> 6, d = i & 63;
    sx[d][r] = X[((size_t)b * TQ + t0 + r) * D + h * HD + d];
    sp[d][r] = POS[(size_t)r * D + h * HD + d];
  }
  __syncthreads();
  const int tx = tid & 15, ty = tid >> 4;
  float acc[4][4] = {};
  for (int d = 0; d < 64; d++) {
    float4 a4 = *(const float4*)&sx[d][ty * 4];
    float4 b4 = *(const float4*)&sp[d][tx * 4];
    float av[4] = {a4.x, a4.y, a4.z, a4.w};
    float bv[4] = {b4.x, b4.y, b4.z, b4.w};
    #pragma unroll
    for (int i = 0; i < 4; i++)
      #pragma unroll
      for (int j = 0; j < 4; j++)
        acc[i][j] += av[i] * bv[j];
  }
  #pragma unroll
  for (int i = 0; i < 4; i++)
    #pragma unroll
    for (int j = 0; j < 4; j++)
      out[((size_t)bh * TQ + t0 + ty * 4 + i) * P + tx * 4 + j] = acc[i][j];
}

// ---------------- flash-style attention with disentangled bias ----------------
__global__ __launch_bounds__(256) void attn_kernel(
    const float* __restrict__ qb, const float* __restrict__ kb, const float* __restrict__ vb,
    const float* __restrict__ c2p, const float* __restrict__ p2c,
    const unsigned char* __restrict__ mask, const unsigned char* __restrict__ tab,
    float* __restrict__ ctx) {
  const int bh = blockIdx.y, b = bh >> 4, h = bh & 15;
  const int q0 = blockIdx.x * 16;
  const int tid = threadIdx.x;

  __shared__ __align__(16) float sq[16][65];
  __shared__ __align__(16) float sc2p[16][68];
  __shared__ __align__(16) float skT[64][68];
  __shared__ __align__(16) float sv[64][68];
  __shared__ __align__(16) float sp2c[64][68];
  __shared__ __align__(16) float ss[16][68];
  __shared__ __align__(16) float sacc[16][68];
  __shared__ float sm[16], sl[16], sfac[16];
  __shared__ unsigned char stab[2048];
  __shared__ unsigned char smask[64];

  for (int i = tid; i < 1024; i += 256) {
    int qi = i >> 6, d = i & 63;
    sq[qi][d]   = qb[((size_t)b * TQ + q0 + qi) * D + h * HD + d];
    sc2p[qi][d] = c2p[((size_t)bh * TQ + q0 + qi) * P + d];
    sacc[qi][d] = 0.f;
  }
  for (int i = tid; i < 2047; i += 256) stab[i] = tab[i];
  if (tid < 16) { sm[tid] = NEG_INF; sl[tid] = 0.f; }

  const float inv_s  = 0.07216878364870323f;  // 1/sqrt(192)
  const float inv_ps = 0.08838834764831845f;  // 1/sqrt(128)
  const int qi = tid >> 4, tx = tid & 15;

  for (int kt = 0; kt < TKV / 64; kt++) {
    const int k0 = kt * 64;
    __syncthreads();
    for (int i = tid; i < 4096; i += 256) {
      int kj = i >> 6, d = i & 63;
      size_t g = ((size_t)b * TKV + k0 + kj) * D + h * HD + d;
      skT[d][kj]  = kb[g];
      sv[kj][d]   = vb[g];
      sp2c[kj][d] = p2c[((size_t)bh * TKV + k0 + kj) * P + d];
    }
    if (tid < 64) smask[tid] = mask[(size_t)b * TKV + k0 + tid];
    __syncthreads();

    const int kj0 = tx * 4;
    float s0 = 0, s1 = 0, s2 = 0, s3 = 0;
    #pragma unroll
    for (int d = 0; d < 64; d++) {
      float a = sq[qi][d];
      float4 bk = *(const float4*)&skT[d][kj0];
      s0 += a * bk.x; s1 += a * bk.y; s2 += a * bk.z; s3 += a * bk.w;
    }
    float val[4] = {s0, s1, s2, s3};
    float lmax = NEG_INF;
    #pragma unroll
    for (int j = 0; j < 4; j++) {
      int kj = kj0 + j;
      int delta = (q0 + qi) - (k0 + kj) + 1023;
      int tbi = stab[delta];
      float vv = val[j] * inv_s + (sc2p[qi][tbi] + sp2c[kj][tbi]) * inv_ps;
      if (smask[kj]) vv = NEG_INF;
      val[j] = vv;
      lmax = fmaxf(lmax, vv);
    }
    #pragma unroll
    for (int off = 1; off < 16; off <<= 1) lmax = fmaxf(lmax, __shfl_xor(lmax, off));
    float mold = sm[qi];
    float mnew = fmaxf(mold, lmax);
    float p[4], psum = 0.f;
    #pragma unroll
    for (int j = 0; j < 4; j++) { p[j] = __expf(val[j] - mnew); psum += p[j]; }
    #pragma unroll
    for (int off = 1; off < 16; off <<= 1) psum += __shfl_xor(psum, off);
    float fac = __expf(mold - mnew);
    if (tx == 0) { sm[qi] = mnew; sl[qi] = sl[qi] * fac + psum; sfac[qi] = fac; }
    *(float4*)&ss[qi][kj0] = make_float4(p[0], p[1], p[2], p[3]);
    __syncthreads();

    const int d0 = tx * 4;
    float fac2 = sfac[qi];
    float4 a4 = *(float4*)&sacc[qi][d0];
    a4.x *= fac2; a4.y *= fac2; a4.z *= fac2; a4.w *= fac2;
    #pragma unroll
    for (int j = 0; j < 64; j++) {
      float pj = ss[qi][j];
      float4 vv = *(const float4*)&sv[j][d0];
      a4.x += pj * vv.x; a4.y += pj * vv.y; a4.z += pj * vv.z; a4.w += pj * vv.w;
    }
    *(float4*)&sacc[qi][d0] = a4;
  }
  __syncthreads();
  const int d0 = tx * 4;
  float invl = 1.0f / sl[qi];
  float4 a4 = *(float4*)&sacc[qi][d0];
  float4 o = make_float4(a4.x * invl, a4.y * invl, a4.z * invl, a4.w * invl);
  *(float4*)&ctx[((size_t)b * TQ + q0 + qi) * D + h * HD + d0] = o;
}

extern "C" void kernel_launch(void* const* d_in, const int* in_sizes, int n_in,
                              void* d_out, int out_size, void* d_ws, size_t ws_size,
                              hipStream_t stream) {
  const float* query = (const float*)d_in[0];
  const float* kv    = (const float*)d_in[1];
  const float* Wq  = (const float*)d_in[2];   const float* bq  = (const float*)d_in[3];
  const float* Wk  = (const float*)d_in[4];   const float* bk  = (const float*)d_in[5];
  const float* Wv  = (const float*)d_in[6];   const float* bv  = (const float*)d_in[7];
  const float* Wo  = (const float*)d_in[8];   const float* bo  = (const float*)d_in[9];
  const float* Wpk = (const float*)d_in[10];  const float* bpk = (const float*)d_in[11];
  const float* Wpq = (const float*)d_in[12];  const float* bpq = (const float*)d_in[13];
  const float* rel_emb = (const float*)d_in[14];
  const float* ln_g = (const float*)d_in[15];
  const float* ln_b = (const float*)d_in[16];
  const unsigned char* amask = (const unsigned char*)d_in[17];

  float* ws = (float*)d_ws;
  float* qbuf   = ws + Q_OFF;
  float* kbuf   = ws + K_OFF;
  float* vbuf   = ws + V_OFF;
  float* ctxbuf = ws + CTX_OFF;
  float* rebuf  = ws + RE_OFF;
  float* poskbuf = ws + POSK_OFF;
  float* posqbuf = ws + POSQ_OFF;
  float* c2pbuf = ws + C2P_OFF;
  float* p2cbuf = ws + P2C_OFF;
  unsigned char* tab = (unsigned char*)d_ws + TAB_OFF_BYTES;

  // 1. LayerNorm of rel_emb
  ln_kernel<<<64, 256, 0, stream>>>(rel_emb, ln_g, ln_b, rebuf);
  // 2. bucket table
  tab_kernel<<<8, 256, 0, stream>>>(tab);
  // 3. positional projections (64 x 1024 @ 1024 x 1024^T) - tiny, fp32
  gemm_bias<<<dim3(16, 1), 256, 0, stream>>>(rebuf, Wpk, bpk, poskbuf, 64, 1024, 1024);
  gemm_bias<<<dim3(16, 1), 256, 0, stream>>>(rebuf, Wpq, bpq, posqbuf, 64, 1024, 1024);
  // 4. Q/K/V projections fused: one launch, blockIdx.z = {q,k,v}
  gemm_split<<<dim3(16, 16, 3), 256, 0, stream>>>(
      query, kv, kv,  Wq, Wk, Wv,  bq, bk, bv,  qbuf, kbuf, vbuf, 2048, 1024, 1024);
  // 5. c2p = q . pos_k, p2c = k . pos_q (per b,h)
  relproj_kernel<<<dim3(16, 32), 256, 0, stream>>>(qbuf, poskbuf, c2pbuf);
  relproj_kernel<<<dim3(16, 32), 256, 0, stream>>>(kbuf, posqbuf, p2cbuf);
  // 6. attention
  attn_kernel<<<dim3(64, 32), 256, 0, stream>>>(qbuf, kbuf, vbuf, c2pbuf, p2cbuf,
                                                amask, tab, ctxbuf);
  // 7. output projection -> d_out
  gemm_split<<<dim3(16, 16, 1), 256, 0, stream>>>(
      ctxbuf, ctxbuf, ctxbuf,  Wo, Wo, Wo,  bo, bo, bo,
      (float*)d_out, (float*)d_out, (float*)d_out, 2048, 1024, 1024);
}

// Round 4
// 291.810 us; speedup vs baseline: 3.4442x; 2.2098x over previous
//
#include <hip/hip_runtime.h>
#include <hip/hip_bf16.h>
#include <math.h>

#define B   2
#define TQ  1024
#define TKV 1024
#define D   1024
#define H   16
#define HD  64
#define P   64     // 2*SPAN
#define SPAN 32

#define NEG_INF (-3.0e38f)

typedef __attribute__((ext_vector_type(8))) short bf16x8;
typedef __attribute__((ext_vector_type(4))) float f32x4;

// ---------------- workspace layout (in floats) ----------------
static constexpr size_t Q_OFF    = 0;
static constexpr size_t K_OFF    = Q_OFF + (size_t)2048 * 1024;
static constexpr size_t VT_OFF   = K_OFF + (size_t)2048 * 1024;     // vt[bh][d][t] = 2M floats
static constexpr size_t CTX_OFF  = VT_OFF + (size_t)2048 * 1024;
static constexpr size_t RE_OFF   = CTX_OFF + (size_t)2048 * 1024;   // 64*1024
static constexpr size_t POSK_OFF = RE_OFF + (size_t)64 * 1024;
static constexpr size_t POSQ_OFF = POSK_OFF + (size_t)64 * 1024;
static constexpr size_t C2P_OFF  = POSQ_OFF + (size_t)64 * 1024;    // B*H*TQ*P = 2M floats
static constexpr size_t P2C_OFF  = C2P_OFF + (size_t)B * H * TQ * P;
static constexpr size_t WS_FLOATS = P2C_OFF + (size_t)B * H * TKV * P;
static constexpr size_t TAB_OFF_BYTES = WS_FLOATS * sizeof(float);  // 2047 uchar

// split x into hi (bit-truncated bf16) + lo (RN bf16 of exact residual)
__device__ __forceinline__ void split2(float x, unsigned short& h, unsigned short& l) {
  unsigned int u = __float_as_uint(x);
  h = (unsigned short)(u >> 16);
  float r = x - __uint_as_float(u & 0xffff0000u);   // exact
  unsigned int v = __float_as_uint(r);
  v += 0x7fffu + ((v >> 16) & 1u);                  // RN-even
  l = (unsigned short)(v >> 16);
}

__device__ __forceinline__ unsigned short bf16rn(float x) {
  unsigned int v = __float_as_uint(x);
  v += 0x7fffu + ((v >> 16) & 1u);
  return (unsigned short)(v >> 16);
}

// ---------------- LayerNorm over rel_emb rows ----------------
__global__ __launch_bounds__(256) void ln_kernel(const float* __restrict__ x,
    const float* __restrict__ g, const float* __restrict__ bta, float* __restrict__ out) {
  const int row = blockIdx.x;
  const float* xr = x + (size_t)row * D;
  const int tid = threadIdx.x;
  __shared__ float red[4];
  float s = 0.f;
  for (int i = tid; i < D; i += 256) s += xr[i];
  #pragma unroll
  for (int off = 32; off; off >>= 1) s += __shfl_down(s, off);
  if ((tid & 63) == 0) red[tid >> 6] = s;
  __syncthreads();
  float mu = (red[0] + red[1] + red[2] + red[3]) * (1.0f / D);
  __syncthreads();
  float vs = 0.f;
  for (int i = tid; i < D; i += 256) { float dd = xr[i] - mu; vs += dd * dd; }
  #pragma unroll
  for (int off = 32; off; off >>= 1) vs += __shfl_down(vs, off);
  if ((tid & 63) == 0) red[tid >> 6] = vs;
  __syncthreads();
  float var = (red[0] + red[1] + red[2] + red[3]) * (1.0f / D);
  float rs = rsqrtf(var + 1e-5f);
  for (int i = tid; i < D; i += 256)
    out[(size_t)row * D + i] = (xr[i] - mu) * rs * g[i] + bta[i];
}

// ---------------- log-bucket position table ----------------
__global__ void tab_kernel(unsigned char* __restrict__ tab) {
  int i = blockIdx.x * 256 + threadIdx.x;
  if (i >= 2047) return;
  int d = i - 1023;
  int ad = d < 0 ? -d : d;
  int bucket;
  if (ad <= 16) {
    bucket = d;
  } else {
    double x = log((double)ad / 16.0) / log(127.0 / 16.0) * 15.0;
    double xr = floor(x + 0.5);
    double xc = (fabs(x - xr) < 1e-9) ? xr : ceil(x);
    int li = (int)xc + 16;
    bucket = (d > 0) ? li : -li;
  }
  int t = bucket + SPAN;
  t = t < 0 ? 0 : (t > 63 ? 63 : t);
  tab[i] = (unsigned char)t;
}

// ---------------- fp32 GEMM for the two 64-row pos projections (z-fused) ----------------
__global__ __launch_bounds__(256) void gemm_bias_pos(const float* __restrict__ A,
    const float* __restrict__ W0, const float* __restrict__ b0, float* __restrict__ C0,
    const float* __restrict__ W1, const float* __restrict__ b1, float* __restrict__ C1,
    int M, int N, int K) {
  const float* W = blockIdx.z ? W1 : W0;
  const float* bias = blockIdx.z ? b1 : b0;
  float* C = blockIdx.z ? C1 : C0;
  __shared__ __align__(16) float As[16][64];
  __shared__ __align__(16) float Ws[16][64];
  const int tid = threadIdx.x;
  const int bm = blockIdx.y * 64, bn = blockIdx.x * 64;
  const int tx = tid & 15, ty = tid >> 4;
  const int lm = tid >> 4, lk = tid & 15;
  float acc[4][4] = {};
  for (int k0 = 0; k0 < K; k0 += 16) {
    __syncthreads();
    #pragma unroll
    for (int r = 0; r < 4; r++) {
      As[lk][lm + 16 * r] = A[(size_t)(bm + lm + 16 * r) * K + k0 + lk];
      Ws[lk][lm + 16 * r] = W[(size_t)(bn + lm + 16 * r) * K + k0 + lk];
    }
    __syncthreads();
    #pragma unroll
    for (int kk = 0; kk < 16; kk++) {
      float4 a4 = *(const float4*)&As[kk][ty * 4];
      float4 b4 = *(const float4*)&Ws[kk][tx * 4];
      float av[4] = {a4.x, a4.y, a4.z, a4.w};
      float bv[4] = {b4.x, b4.y, b4.z, b4.w};
      #pragma unroll
      for (int i = 0; i < 4; i++)
        #pragma unroll
        for (int j = 0; j < 4; j++)
          acc[i][j] += av[i] * bv[j];
    }
  }
  #pragma unroll
  for (int i = 0; i < 4; i++) {
    int m = bm + ty * 4 + i;
    #pragma unroll
    for (int j = 0; j < 4; j++) {
      int n = bn + tx * 4 + j;
      C[(size_t)m * N + n] = acc[i][j] + bias[n];
    }
  }
}

// ---------------- split-bf16 MFMA GEMM: C[M,N] = A @ W^T + bias ----------------
// BM=128, BN=64, BK=32, 256 threads = 4 waves (2x2), wave tile 64x32.
// If z == vtz, store transposed as C[((b*16+h)*64+d)*1024 + t] (for V).
__global__ __launch_bounds__(256) void gemm_split(
    const float* __restrict__ A0, const float* __restrict__ A1, const float* __restrict__ A2,
    const float* __restrict__ W0, const float* __restrict__ W1, const float* __restrict__ W2,
    const float* __restrict__ b0, const float* __restrict__ b1, const float* __restrict__ b2,
    float* __restrict__ C0, float* __restrict__ C1, float* __restrict__ C2,
    int M, int N, int K, int vtz) {
  const int z = blockIdx.z;
  const float* A = (z == 0) ? A0 : (z == 1) ? A1 : A2;
  const float* W = (z == 0) ? W0 : (z == 1) ? W1 : W2;
  const float* bias = (z == 0) ? b0 : (z == 1) ? b1 : b2;
  float* C = (z == 0) ? C0 : (z == 1) ? C1 : C2;

  __shared__ short sAhi[128 * 32];
  __shared__ short sAlo[128 * 32];
  __shared__ short sBhi[64 * 32];
  __shared__ short sBlo[64 * 32];

  const int t = threadIdx.x;
  const int bm = blockIdx.y * 128, bn = blockIdx.x * 64;
  const int wid = t >> 6, lane = t & 63;
  const int wr = wid >> 1, wc = wid & 1;
  const int fr = lane & 15, fo = (lane >> 4) * 8;

  f32x4 acc[4][2];
  #pragma unroll
  for (int i = 0; i < 4; i++)
    #pragma unroll
    for (int j = 0; j < 2; j++)
      acc[i][j] = (f32x4){0.f, 0.f, 0.f, 0.f};

  const int srow = t >> 3;          // 0..31
  const int scol = (t & 7) * 4;     // 0,4,..,28

  for (int k0 = 0; k0 < K; k0 += 32) {
    #pragma unroll
    for (int i = 0; i < 4; i++) {
      int row = srow + 32 * i;
      float4 a = *(const float4*)&A[(size_t)(bm + row) * K + k0 + scol];
      unsigned short h0, h1, h2, h3, l0, l1, l2, l3;
      split2(a.x, h0, l0); split2(a.y, h1, l1); split2(a.z, h2, l2); split2(a.w, h3, l3);
      *(short4*)&sAhi[row * 32 + scol] = make_short4((short)h0, (short)h1, (short)h2, (short)h3);
      *(short4*)&sAlo[row * 32 + scol] = make_short4((short)l0, (short)l1, (short)l2, (short)l3);
    }
    #pragma unroll
    for (int i = 0; i < 2; i++) {
      int row = srow + 32 * i;
      float4 a = *(const float4*)&W[(size_t)(bn + row) * K + k0 + scol];
      unsigned short h0, h1, h2, h3, l0, l1, l2, l3;
      split2(a.x, h0, l0); split2(a.y, h1, l1); split2(a.z, h2, l2); split2(a.w, h3, l3);
      *(short4*)&sBhi[row * 32 + scol] = make_short4((short)h0, (short)h1, (short)h2, (short)h3);
      *(short4*)&sBlo[row * 32 + scol] = make_short4((short)l0, (short)l1, (short)l2, (short)l3);
    }
    __syncthreads();

    bf16x8 ah[4], al[4], bh[2], bl[2];
    #pragma unroll
    for (int mf = 0; mf < 4; mf++) {
      int r = (wr * 64 + mf * 16 + fr) * 32 + fo;
      ah[mf] = *(const bf16x8*)&sAhi[r];
      al[mf] = *(const bf16x8*)&sAlo[r];
    }
    #pragma unroll
    for (int nf = 0; nf < 2; nf++) {
      int r = (wc * 32 + nf * 16 + fr) * 32 + fo;
      bh[nf] = *(const bf16x8*)&sBhi[r];
      bl[nf] = *(const bf16x8*)&sBlo[r];
    }
    #pragma unroll
    for (int mf = 0; mf < 4; mf++)
      #pragma unroll
      for (int nf = 0; nf < 2; nf++) {
        acc[mf][nf] = __builtin_amdgcn_mfma_f32_16x16x32_bf16(ah[mf], bh[nf], acc[mf][nf], 0, 0, 0);
        acc[mf][nf] = __builtin_amdgcn_mfma_f32_16x16x32_bf16(ah[mf], bl[nf], acc[mf][nf], 0, 0, 0);
        acc[mf][nf] = __builtin_amdgcn_mfma_f32_16x16x32_bf16(al[mf], bh[nf], acc[mf][nf], 0, 0, 0);
      }
    __syncthreads();
  }

  if (z == vtz) {
    // transposed store: rows m = tokens (b*1024+t), cols n = features (h*64+d)
    // -> C[((b*16+h)*64+d)*1024 + t]; acc regs r=0..3 are consecutive t -> float4
    #pragma unroll
    for (int mf = 0; mf < 4; mf++) {
      int m0 = bm + wr * 64 + mf * 16 + (lane >> 4) * 4;
      int bb2 = m0 >> 10, t0 = m0 & 1023;
      #pragma unroll
      for (int nf = 0; nf < 2; nf++) {
        int col = bn + wc * 32 + nf * 16 + fr;
        int hh = col >> 6, dd = col & 63;
        float bv = bias[col];
        float4 o = make_float4(acc[mf][nf][0] + bv, acc[mf][nf][1] + bv,
                               acc[mf][nf][2] + bv, acc[mf][nf][3] + bv);
        *(float4*)&C[(((size_t)bb2 * 16 + hh) * 64 + dd) * 1024 + t0] = o;
      }
    }
  } else {
    #pragma unroll
    for (int mf = 0; mf < 4; mf++) {
      int rbase = bm + wr * 64 + mf * 16 + (lane >> 4) * 4;
      #pragma unroll
      for (int nf = 0; nf < 2; nf++) {
        int col = bn + wc * 32 + nf * 16 + fr;
        float bb = bias[col];
        #pragma unroll
        for (int r = 0; r < 4; r++)
          C[(size_t)(rbase + r) * N + col] = acc[mf][nf][r] + bb;
      }
    }
  }
}

// ---------------- rel projection (z-fused: z0 = q.posk -> c2p, z1 = k.posq -> p2c) ----
__global__ __launch_bounds__(256) void relproj_kernel(
    const float* __restrict__ X0, const float* __restrict__ P0, float* __restrict__ O0,
    const float* __restrict__ X1, const float* __restrict__ P1, float* __restrict__ O1) {
  const float* X = blockIdx.z ? X1 : X0;
  const float* POS = blockIdx.z ? P1 : P0;
  float* out = blockIdx.z ? O1 : O0;
  const int bh = blockIdx.y, b = bh >> 4, h = bh & 15;
  const int t0 = blockIdx.x * 64;
  __shared__ __align__(16) float sx[64][68];
  __shared__ __align__(16) float sp[64][68];
  const int tid = threadIdx.x;
  for (int i = tid; i < 4096; i += 256) {
    int r = i >> 6, d = i & 63;
    sx[d][r] = X[((size_t)b * TQ + t0 + r) * D + h * HD + d];
    sp[d][r] = POS[(size_t)r * D + h * HD + d];
  }
  __syncthreads();
  const int tx = tid & 15, ty = tid >> 4;
  float acc[4][4] = {};
  for (int d = 0; d < 64; d++) {
    float4 a4 = *(const float4*)&sx[d][ty * 4];
    float4 b4 = *(const float4*)&sp[d][tx * 4];
    float av[4] = {a4.x, a4.y, a4.z, a4.w};
    float bv[4] = {b4.x, b4.y, b4.z, b4.w};
    #pragma unroll
    for (int i = 0; i < 4; i++)
      #pragma unroll
      for (int j = 0; j < 4; j++)
        acc[i][j] += av[i] * bv[j];
  }
  #pragma unroll
  for (int i = 0; i < 4; i++)
    #pragma unroll
    for (int j = 0; j < 4; j++)
      out[((size_t)bh * TQ + t0 + ty * 4 + i) * P + tx * 4 + j] = acc[i][j];
}

// ---------------- MFMA flash attention with disentangled bias ----------------
// grid (TQ/64, B*H), 256 threads = 4 waves; wave w owns q rows q0+w*16..+15.
// Swapped QK^T: S^T = mfma(A=K, B=Q) -> lane&15 = q, rows = kj.
__global__ __launch_bounds__(256) void attn_mfma(
    const float* __restrict__ qb, const float* __restrict__ kb, const float* __restrict__ vt,
    const float* __restrict__ c2p, const float* __restrict__ p2c,
    const unsigned char* __restrict__ mask, const unsigned char* __restrict__ tab,
    float* __restrict__ ctx) {
  const int bh = blockIdx.y, b = bh >> 4, h = bh & 15;
  const int q0 = blockIdx.x * 64;
  const int tid = threadIdx.x;
  const int wid = tid >> 6, lane = tid & 63;
  const int g = lane >> 4, fr = lane & 15;

  __shared__ __align__(16) short sKh[64][72];
  __shared__ __align__(16) short sKl[64][72];
  __shared__ __align__(16) short sVh[64][72];   // [d][kj]
  __shared__ __align__(16) short sVl[64][72];
  __shared__ __align__(16) float sc2p[64][68];
  __shared__ __align__(16) float sp2c[64][68];
  __shared__ unsigned char stab[2048];
  __shared__ unsigned char smask[64];

  // --- Q fragments, direct from global, kept in registers all 16 iters
  bf16x8 qh[2], ql[2];
  {
    const int qrow = q0 + wid * 16 + fr;
    const float* qp = qb + ((size_t)b * TQ + qrow) * D + h * HD + g * 8;
    #pragma unroll
    for (int ks = 0; ks < 2; ks++) {
      float4 x0 = *(const float4*)(qp + ks * 32);
      float4 x1 = *(const float4*)(qp + ks * 32 + 4);
      float xs[8] = {x0.x, x0.y, x0.z, x0.w, x1.x, x1.y, x1.z, x1.w};
      bf16x8 th, tl;
      #pragma unroll
      for (int j = 0; j < 8; j++) {
        unsigned short hh, ll;
        split2(xs[j], hh, ll);
        th[j] = (short)hh; tl[j] = (short)ll;
      }
      qh[ks] = th; ql[ks] = tl;
    }
  }

  const int r = tid >> 2;            // 0..63 staging row
  const int cb = (tid & 3) * 16;     // staging col block

  // --- stage c2p tile (once) + bucket table
  {
    const float* cp = c2p + ((size_t)bh * TQ + q0 + r) * P + cb;
    #pragma unroll
    for (int cc = 0; cc < 4; cc++)
      *(float4*)&sc2p[r][cb + cc * 4] = *(const float4*)(cp + cc * 4);
  }
  for (int i = tid; i < 2047; i += 256) stab[i] = tab[i];

  f32x4 acc[4];
  #pragma unroll
  for (int nf = 0; nf < 4; nf++) acc[nf] = (f32x4){0.f, 0.f, 0.f, 0.f};
  float m_run = NEG_INF, l_run = 0.f;

  const float inv_s  = 0.07216878364870323f;  // 1/sqrt(192)
  const float inv_ps = 0.08838834764831845f;  // 1/sqrt(128)
  const int qloc = wid * 16 + fr;

  for (int kt = 0; kt < TKV / 64; kt++) {
    const int k0 = kt * 64;
    __syncthreads();
    // --- stage K (hi/lo), V^T (hi/lo), p2c tile
    {
      const float* kp = kb + ((size_t)b * TKV + k0 + r) * D + h * HD + cb;
      const float* vp = vt + ((size_t)bh * HD + r) * TKV + k0 + cb;
      const float* pp = p2c + ((size_t)bh * TKV + k0 + r) * P + cb;
      #pragma unroll
      for (int cc = 0; cc < 4; cc++) {
        float4 kk = *(const float4*)(kp + cc * 4);
        unsigned short h0, h1, h2, h3, l0, l1, l2, l3;
        split2(kk.x, h0, l0); split2(kk.y, h1, l1); split2(kk.z, h2, l2); split2(kk.w, h3, l3);
        *(short4*)&sKh[r][cb + cc * 4] = make_short4((short)h0, (short)h1, (short)h2, (short)h3);
        *(short4*)&sKl[r][cb + cc * 4] = make_short4((short)l0, (short)l1, (short)l2, (short)l3);
        float4 vv = *(const float4*)(vp + cc * 4);
        split2(vv.x, h0, l0); split2(vv.y, h1, l1); split2(vv.z, h2, l2); split2(vv.w, h3, l3);
        *(short4*)&sVh[r][cb + cc * 4] = make_short4((short)h0, (short)h1, (short)h2, (short)h3);
        *(short4*)&sVl[r][cb + cc * 4] = make_short4((short)l0, (short)l1, (short)l2, (short)l3);
        *(float4*)&sp2c[r][cb + cc * 4] = *(const float4*)(pp + cc * 4);
      }
      if (tid < 64) smask[tid] = mask[(size_t)b * TKV + k0 + tid];
    }
    __syncthreads();

    // --- S^T = K.Q^T (split bf16: 3 terms)
    f32x4 st[4];
    #pragma unroll
    for (int mf = 0; mf < 4; mf++) st[mf] = (f32x4){0.f, 0.f, 0.f, 0.f};
    #pragma unroll
    for (int mf = 0; mf < 4; mf++) {
      #pragma unroll
      for (int ks = 0; ks < 2; ks++) {
        bf16x8 kh = *(const bf16x8*)&sKh[mf * 16 + fr][g * 8 + ks * 32];
        bf16x8 kl = *(const bf16x8*)&sKl[mf * 16 + fr][g * 8 + ks * 32];
        st[mf] = __builtin_amdgcn_mfma_f32_16x16x32_bf16(kh, qh[ks], st[mf], 0, 0, 0);
        st[mf] = __builtin_amdgcn_mfma_f32_16x16x32_bf16(kh, ql[ks], st[mf], 0, 0, 0);
        st[mf] = __builtin_amdgcn_mfma_f32_16x16x32_bf16(kl, qh[ks], st[mf], 0, 0, 0);
      }
    }

    // --- bias + mask + online softmax (q = fr per lane; kj = mf*16 + g*4 + rr)
    const int dq = q0 + qloc - k0 + 1023;
    float pv[4][4];
    float lmax = NEG_INF;
    #pragma unroll
    for (int mf = 0; mf < 4; mf++) {
      #pragma unroll
      for (int rr = 0; rr < 4; rr++) {
        int kj = mf * 16 + g * 4 + rr;
        int tbi = stab[dq - kj];
        float v = st[mf][rr] * inv_s + (sc2p[qloc][tbi] + sp2c[kj][tbi]) * inv_ps;
        v = smask[kj] ? NEG_INF : v;
        pv[mf][rr] = v;
        lmax = fmaxf(lmax, v);
      }
    }
    lmax = fmaxf(lmax, __shfl_xor(lmax, 16));
    lmax = fmaxf(lmax, __shfl_xor(lmax, 32));
    float mnew = fmaxf(m_run, lmax);
    float fac = __expf(m_run - mnew);
    m_run = mnew;
    float psum = 0.f;
    #pragma unroll
    for (int mf = 0; mf < 4; mf++)
      #pragma unroll
      for (int rr = 0; rr < 4; rr++) {
        float e = __expf(pv[mf][rr] - mnew);
        pv[mf][rr] = e;
        psum += e;
      }
    psum += __shfl_xor(psum, 16);
    psum += __shfl_xor(psum, 32);
    l_run = l_run * fac + psum;

    // --- rescale ctx accumulators (acc rows are q = g*4 + rr)
    float facr[4];
    #pragma unroll
    for (int rr = 0; rr < 4; rr++) facr[rr] = __shfl(fac, g * 4 + rr);
    #pragma unroll
    for (int nf = 0; nf < 4; nf++)
      #pragma unroll
      for (int rr = 0; rr < 4; rr++) acc[nf][rr] *= facr[rr];

    // --- build P A-fragments via shfl gather:
    // dst lane (g,fr) elem (ks,j) needs P[q=fr][kj=32ks+8g+j]
    //   = pv[2ks+(g>>1)][j&3] held by lane (2(g&1)+(j>>2))*16 + fr
    bf16x8 pa[2];
    #pragma unroll
    for (int ks = 0; ks < 2; ks++) {
      bf16x8 t;
      #pragma unroll
      for (int j = 0; j < 8; j++) {
        int src = ((2 * (g & 1) + (j >> 2)) << 4) | fr;
        float v0 = __shfl(pv[2 * ks][j & 3], src);
        float v1 = __shfl(pv[2 * ks + 1][j & 3], src);
        float pvv = (g >> 1) ? v1 : v0;
        t[j] = (short)bf16rn(pvv);
      }
      pa[ks] = t;
    }

    // --- ctx += P.V (V split hi+lo)
    #pragma unroll
    for (int nf = 0; nf < 4; nf++) {
      #pragma unroll
      for (int ks = 0; ks < 2; ks++) {
        bf16x8 vh = *(const bf16x8*)&sVh[nf * 16 + fr][g * 8 + ks * 32];
        bf16x8 vl = *(const bf16x8*)&sVl[nf * 16 + fr][g * 8 + ks * 32];
        acc[nf] = __builtin_amdgcn_mfma_f32_16x16x32_bf16(pa[ks], vh, acc[nf], 0, 0, 0);
        acc[nf] = __builtin_amdgcn_mfma_f32_16x16x32_bf16(pa[ks], vl, acc[nf], 0, 0, 0);
      }
    }
  }

  // --- epilogue: normalize and store (acc rows q = g*4+rr, cols d = nf*16+fr)
  float invl[4];
  #pragma unroll
  for (int rr = 0; rr < 4; rr++) invl[rr] = 1.0f / __shfl(l_run, g * 4 + rr);
  #pragma unroll
  for (int nf = 0; nf < 4; nf++) {
    #pragma unroll
    for (int rr = 0; rr < 4; rr++) {
      int qrow = q0 + wid * 16 + g * 4 + rr;
      int dcol = h * HD + nf * 16 + fr;
      ctx[((size_t)b * TQ + qrow) * D + dcol] = acc[nf][rr] * invl[rr];
    }
  }
}

extern "C" void kernel_launch(void* const* d_in, const int* in_sizes, int n_in,
                              void* d_out, int out_size, void* d_ws, size_t ws_size,
                              hipStream_t stream) {
  const float* query = (const float*)d_in[0];
  const float* kv    = (const float*)d_in[1];
  const float* Wq  = (const float*)d_in[2];   const float* bq  = (const float*)d_in[3];
  const float* Wk  = (const float*)d_in[4];   const float* bk  = (const float*)d_in[5];
  const float* Wv  = (const float*)d_in[6];   const float* bv  = (const float*)d_in[7];
  const float* Wo  = (const float*)d_in[8];   const float* bo  = (const float*)d_in[9];
  const float* Wpk = (const float*)d_in[10];  const float* bpk = (const float*)d_in[11];
  const float* Wpq = (const float*)d_in[12];  const float* bpq = (const float*)d_in[13];
  const float* rel_emb = (const float*)d_in[14];
  const float* ln_g = (const float*)d_in[15];
  const float* ln_b = (const float*)d_in[16];
  const unsigned char* amask = (const unsigned char*)d_in[17];

  float* ws = (float*)d_ws;
  float* qbuf   = ws + Q_OFF;
  float* kbuf   = ws + K_OFF;
  float* vtbuf  = ws + VT_OFF;
  float* ctxbuf = ws + CTX_OFF;
  float* rebuf  = ws + RE_OFF;
  float* poskbuf = ws + POSK_OFF;
  float* posqbuf = ws + POSQ_OFF;
  float* c2pbuf = ws + C2P_OFF;
  float* p2cbuf = ws + P2C_OFF;
  unsigned char* tab = (unsigned char*)d_ws + TAB_OFF_BYTES;

  // 1. LayerNorm of rel_emb + bucket table
  ln_kernel<<<64, 256, 0, stream>>>(rel_emb, ln_g, ln_b, rebuf);
  tab_kernel<<<8, 256, 0, stream>>>(tab);
  // 2. positional projections (64 x 1024 @ 1024^2), z-fused
  gemm_bias_pos<<<dim3(16, 1, 2), 256, 0, stream>>>(rebuf, Wpk, bpk, poskbuf,
                                                    Wpq, bpq, posqbuf, 64, 1024, 1024);
  // 3. Q/K/V projections fused; V stored transposed into vt[bh][d][t]
  gemm_split<<<dim3(16, 16, 3), 256, 0, stream>>>(
      query, kv, kv,  Wq, Wk, Wv,  bq, bk, bv,  qbuf, kbuf, vtbuf, 2048, 1024, 1024, 2);
  // 4. c2p = q . pos_k, p2c = k . pos_q (z-fused)
  relproj_kernel<<<dim3(16, 32, 2), 256, 0, stream>>>(
      qbuf, poskbuf, c2pbuf, kbuf, posqbuf, p2cbuf);
  // 5. MFMA flash attention
  attn_mfma<<<dim3(16, 32), 256, 0, stream>>>(qbuf, kbuf, vtbuf, c2pbuf, p2cbuf,
                                              amask, tab, ctxbuf);
  // 6. output projection -> d_out
  gemm_split<<<dim3(16, 16, 1), 256, 0, stream>>>(
      ctxbuf, ctxbuf, ctxbuf,  Wo, Wo, Wo,  bo, bo, bo,
      (float*)d_out, (float*)d_out, (float*)d_out, 2048, 1024, 1024, -1);
}